// Round 3
// baseline (1812.604 us; speedup 1.0000x reference)
//
#include <hip/hip_runtime.h>
#include <hip/hip_bf16.h>
#include <math.h>

#define N_HIGH 4096
#define N_LOW 262144
#define E_HIGH 65536
#define E_LOW 524288
#define LN_EPS 1e-5f
#define ATT_SCALE 0.17677669529663687f /* 1/sqrt(32) */

__device__ __forceinline__ float bf2f(unsigned int u) {
    union { unsigned int i; float f; } v; v.i = u << 16; return v.f;
}
__device__ __forceinline__ unsigned short f2bf(float f) {
    union { unsigned int i; float f; } v; v.f = f;
    unsigned int r = (v.i + 0x7fffu + ((v.i >> 16) & 1u)) >> 16;
    return (unsigned short)r;
}
// flag-aware scalar load from an external float array (fp32 or bf16 per flag)
__device__ __forceinline__ float ldf(const void* p, size_t i, int isbf) {
    if (isbf) return bf2f(((const unsigned short*)p)[i]);
    return ((const float*)p)[i];
}
// flag-aware float4 load; i must be a multiple of 4
__device__ __forceinline__ float4 load4f(const void* p, size_t i, int isbf) {
    if (isbf) {
        uint2 u = *(const uint2*)((const unsigned short*)p + i);
        float4 r;
        r.x = bf2f(u.x & 0xffffu); r.y = bf2f(u.x >> 16);
        r.z = bf2f(u.y & 0xffffu); r.w = bf2f(u.y >> 16);
        return r;
    }
    return *(const float4*)((const float*)p + i);
}
// flag-aware store to external output
__device__ __forceinline__ void stf(void* p, size_t i, float v, int isbf) {
    if (isbf) ((unsigned short*)p)[i] = f2bf(v);
    else      ((float*)p)[i] = v;
}

// ---------------------------------------------------------------------------
// Dtype probe: bits[8:15] of the first 256 32-bit words of high_emb.
// bf16 gaussian data: that byte is sign|exp[7:1] of an element -> (b&0x7f)
// clusters in [60,65]. fp32 data: mantissa bits -> ~uniform (9% hit rate).
// ---------------------------------------------------------------------------
__global__ __launch_bounds__(256) void probe_dtype_kernel(
    const unsigned int* __restrict__ x, int* __restrict__ flag)
{
    __shared__ int cnt;
    if (threadIdx.x == 0) cnt = 0;
    __syncthreads();
    unsigned int b = (x[threadIdx.x] >> 8) & 0x7fu;
    if (b >= 60u && b <= 65u) atomicAdd(&cnt, 1);
    __syncthreads();
    if (threadIdx.x == 0) *flag = (cnt >= 128) ? 1 : 0;
}

// ---------------------------------------------------------------------------
// Tiled fp32 VALU GEMM with fused dtype conversion.
// Tile 64 rows x 128 cols; grid (M/64, 4) where blockIdx.y picks Wq/Wk/Wv/Ws.
// q,k,v -> bf16 qkv[M,384]; skip -> fp32 accv[M,128].
// ---------------------------------------------------------------------------
__global__ __launch_bounds__(256) void gemm_kernel(
    const void* __restrict__ x,
    const void* __restrict__ Wq, const void* __restrict__ Wk,
    const void* __restrict__ Wv, const void* __restrict__ Ws,
    const void* __restrict__ bq, const void* __restrict__ bk,
    const void* __restrict__ bv, const void* __restrict__ bs,
    unsigned short* __restrict__ qkv, float* __restrict__ accv,
    const int* __restrict__ dflag)
{
    __shared__ float xs[64 * 128];
    const int isbf = *dflag;
    const int t = threadIdx.x;
    const int m0 = blockIdx.x * 64;
    const int g = blockIdx.y;

    // stage x tile (64x128) into LDS as fp32
    #pragma unroll
    for (int i = 0; i < 8; ++i) {
        int linear = i * 256 + t;            // 0..2047
        int row = linear >> 5;               // 0..63
        int kq = (linear & 31) << 2;         // 0,4,...,124
        float4 v = load4f(x, (size_t)(m0 + row) * 128 + kq, isbf);
        *(float4*)&xs[row * 128 + kq] = v;
    }
    __syncthreads();

    const void* W = (g == 0) ? Wq : (g == 1) ? Wk : (g == 2) ? Wv : Ws;
    const void* b = (g == 0) ? bq : (g == 1) ? bk : (g == 2) ? bv : bs;

    const int tx = t & 31;       // 32 col groups of 4
    const int ty = t >> 5;       // 8 row groups of 8
    const int c0 = tx * 4;
    const int r0 = ty * 8;

    float acc[8][4];
    #pragma unroll
    for (int j = 0; j < 8; ++j)
        #pragma unroll
        for (int jj = 0; jj < 4; ++jj) acc[j][jj] = 0.f;

    #pragma unroll 4
    for (int k = 0; k < 128; ++k) {
        float4 w4 = load4f(W, (size_t)k * 128 + c0, isbf);
        #pragma unroll
        for (int j = 0; j < 8; ++j) {
            float a = xs[(r0 + j) * 128 + k];
            acc[j][0] += a * w4.x;
            acc[j][1] += a * w4.y;
            acc[j][2] += a * w4.z;
            acc[j][3] += a * w4.w;
        }
    }

    float bias[4];
    #pragma unroll
    for (int jj = 0; jj < 4; ++jj) bias[jj] = ldf(b, c0 + jj, isbf);

    #pragma unroll
    for (int j = 0; j < 8; ++j) {
        size_t row = (size_t)(m0 + r0 + j);
        float v0 = acc[j][0] + bias[0];
        float v1 = acc[j][1] + bias[1];
        float v2 = acc[j][2] + bias[2];
        float v3 = acc[j][3] + bias[3];
        if (g < 3) {
            uint2 st;
            st.x = (unsigned int)f2bf(v0) | ((unsigned int)f2bf(v1) << 16);
            st.y = (unsigned int)f2bf(v2) | ((unsigned int)f2bf(v3) << 16);
            *(uint2*)&qkv[row * 384 + g * 128 + c0] = st;
        } else {
            float4 st = { v0, v1, v2, v3 };
            *(float4*)&accv[row * 128 + c0] = st;
        }
    }
}

// ---------------------------------------------------------------------------
// Edge pass B: per-head scores -> e = exp(score*scale); denom += e
// ---------------------------------------------------------------------------
__global__ __launch_bounds__(256) void edge_scores_kernel(
    const unsigned short* __restrict__ qkv, const int* __restrict__ ei, int E,
    float* __restrict__ ebuf, float* __restrict__ denom)
{
    int lane = threadIdx.x & 63;
    int e = blockIdx.x * 4 + (threadIdx.x >> 6);
    if (e >= E) return;
    int src = ei[e];
    int dst = ei[E + e];
    const unsigned short* qp = qkv + (long)dst * 384;
    const unsigned short* kp = qkv + (long)src * 384 + 128;
    ushort2 qa = *(const ushort2*)(qp + 2 * lane);
    ushort2 kb = *(const ushort2*)(kp + 2 * lane);
    float partial = bf2f(qa.x) * bf2f(kb.x) + bf2f(qa.y) * bf2f(kb.y);
    #pragma unroll
    for (int m = 1; m < 16; m <<= 1) partial += __shfl_xor(partial, m, 64);
    if ((lane & 15) == 0) {
        int h = lane >> 4;
        float z = partial * ATT_SCALE;
        z = fminf(fmaxf(z, -60.f), 60.f);
        float ev = __expf(z);
        ebuf[(long)e * 4 + h] = ev;
        atomicAdd(&denom[(long)dst * 4 + h], ev);
    }
}

// ---------------------------------------------------------------------------
// Edge pass C: acc[dst] += (e/denom[dst]) * v[src]
// ---------------------------------------------------------------------------
__global__ __launch_bounds__(256) void edge_agg_kernel(
    const unsigned short* __restrict__ qkv, const int* __restrict__ ei, int E,
    const float* __restrict__ ebuf, const float* __restrict__ denom,
    float* __restrict__ acc)
{
    int lane = threadIdx.x & 63;
    int e = blockIdx.x * 4 + (threadIdx.x >> 6);
    if (e >= E) return;
    int src = ei[e];
    int dst = ei[E + e];
    int h = lane >> 4;
    float d = fmaxf(denom[(long)dst * 4 + h], 1e-30f);
    float alpha = ebuf[(long)e * 4 + h] / d;
    ushort2 vv = *(const ushort2*)(qkv + (long)src * 384 + 256 + 2 * lane);
    float* ap = acc + (long)dst * 128 + 2 * lane;
    atomicAdd(ap, alpha * bf2f(vv.x));
    atomicAdd(ap + 1, alpha * bf2f(vv.y));
}

// ---------------------------------------------------------------------------
// LayerNorm + ReLU -> bf16 internal; one wave per node
// ---------------------------------------------------------------------------
__global__ __launch_bounds__(256) void ln_relu_kernel(
    const float* __restrict__ acc, const void* __restrict__ lnw,
    const void* __restrict__ lnb, unsigned short* __restrict__ out, int N,
    const int* __restrict__ dflag)
{
    const int isbf = *dflag;
    int lane = threadIdx.x & 63;
    int n = blockIdx.x * 4 + (threadIdx.x >> 6);
    if (n >= N) return;
    float2 v = *(const float2*)(acc + (long)n * 128 + 2 * lane);
    float s = v.x + v.y;
    float q = v.x * v.x + v.y * v.y;
    #pragma unroll
    for (int m = 1; m < 64; m <<= 1) { s += __shfl_xor(s, m, 64); q += __shfl_xor(q, m, 64); }
    float mean = s * (1.f / 128.f);
    float var = fmaxf(q * (1.f / 128.f) - mean * mean, 0.f);
    float rs = rsqrtf(var + LN_EPS);
    float w0 = ldf(lnw, 2 * lane, isbf), w1 = ldf(lnw, 2 * lane + 1, isbf);
    float b0 = ldf(lnb, 2 * lane, isbf), b1 = ldf(lnb, 2 * lane + 1, isbf);
    float y0 = fmaxf((v.x - mean) * rs * w0 + b0, 0.f);
    float y1 = fmaxf((v.y - mean) * rs * w1 + b1, 0.f);
    unsigned short* o = out + (long)n * 128 + 2 * lane;
    o[0] = f2bf(y0);
    o[1] = f2bf(y1);
}

// ---------------------------------------------------------------------------
// global_mean_pool over sorted batch; one block (128 thr) per high node
// ---------------------------------------------------------------------------
__global__ __launch_bounds__(128) void pool_kernel(
    const unsigned short* __restrict__ l, const int* __restrict__ batch,
    float* __restrict__ pooled)
{
    __shared__ int se[2];
    int g = blockIdx.x;
    if (threadIdx.x == 0) {
        int lo = 0, hi = N_LOW;
        while (lo < hi) { int mid = (lo + hi) >> 1; if (batch[mid] < g) lo = mid + 1; else hi = mid; }
        se[0] = lo;
        hi = N_LOW;
        while (lo < hi) { int mid = (lo + hi) >> 1; if (batch[mid] < g + 1) lo = mid + 1; else hi = mid; }
        se[1] = lo;
    }
    __syncthreads();
    int start = se[0], end = se[1];
    int d = threadIdx.x;
    float ssum = 0.f;
    for (int r = start; r < end; ++r) ssum += bf2f(l[(long)r * 128 + d]);
    int cnt = end - start;
    pooled[(long)g * 128 + d] = ssum / (float)(cnt > 0 ? cnt : 1);
}

// ---------------------------------------------------------------------------
// high_out = sim*h + (1-sim)*pooled, sim = sigmoid([h,pooled]@w_lh)
// ---------------------------------------------------------------------------
__global__ __launch_bounds__(256) void high_out_kernel(
    const unsigned short* __restrict__ h, const float* __restrict__ pooled,
    const void* __restrict__ wlh, void* __restrict__ out,
    const int* __restrict__ dflag)
{
    const int isbf = *dflag;
    int lane = threadIdx.x & 63;
    int n = blockIdx.x * 4 + (threadIdx.x >> 6);
    if (n >= N_HIGH) return;
    float h0 = bf2f(h[(long)n * 128 + 2 * lane]);
    float h1 = bf2f(h[(long)n * 128 + 2 * lane + 1]);
    float2 pv = *(const float2*)(pooled + (long)n * 128 + 2 * lane);
    float s = h0 * ldf(wlh, 2 * lane, isbf) + h1 * ldf(wlh, 2 * lane + 1, isbf)
            + pv.x * ldf(wlh, 128 + 2 * lane, isbf) + pv.y * ldf(wlh, 128 + 2 * lane + 1, isbf);
    #pragma unroll
    for (int m = 1; m < 64; m <<= 1) s += __shfl_xor(s, m, 64);
    float sim = 1.f / (1.f + __expf(-s));
    stf(out, (size_t)n * 128 + 2 * lane,     sim * h0 + (1.f - sim) * pv.x, isbf);
    stf(out, (size_t)n * 128 + 2 * lane + 1, sim * h1 + (1.f - sim) * pv.y, isbf);
}

// ---------------------------------------------------------------------------
// low_out = a*l + (1-a)*h[batch], a = sigmoid([hb,l]@w_hl)
// ---------------------------------------------------------------------------
__global__ __launch_bounds__(256) void low_out_kernel(
    const unsigned short* __restrict__ l, const unsigned short* __restrict__ h,
    const int* __restrict__ batch, const void* __restrict__ whl,
    void* __restrict__ out, const int* __restrict__ dflag)
{
    const int isbf = *dflag;
    int lane = threadIdx.x & 63;
    int n = blockIdx.x * 4 + (threadIdx.x >> 6);
    if (n >= N_LOW) return;
    int g = batch[n];
    float l0 = bf2f(l[(long)n * 128 + 2 * lane]);
    float l1 = bf2f(l[(long)n * 128 + 2 * lane + 1]);
    float h0 = bf2f(h[(long)g * 128 + 2 * lane]);
    float h1 = bf2f(h[(long)g * 128 + 2 * lane + 1]);
    float s = h0 * ldf(whl, 2 * lane, isbf) + h1 * ldf(whl, 2 * lane + 1, isbf)
            + l0 * ldf(whl, 128 + 2 * lane, isbf) + l1 * ldf(whl, 128 + 2 * lane + 1, isbf);
    #pragma unroll
    for (int m = 1; m < 64; m <<= 1) s += __shfl_xor(s, m, 64);
    float a = 1.f / (1.f + __expf(-s));
    size_t base = (size_t)N_HIGH * 128 + (size_t)n * 128 + 2 * lane;
    stf(out, base,     a * l0 + (1.f - a) * h0, isbf);
    stf(out, base + 1, a * l1 + (1.f - a) * h1, isbf);
}

// ---------------------------------------------------------------------------
extern "C" void kernel_launch(void* const* d_in, const int* in_sizes, int n_in,
                              void* d_out, int out_size, void* d_ws, size_t ws_size,
                              hipStream_t stream)
{
    const void* high_emb = d_in[0];
    const void* low_emb  = d_in[1];
    const void* Wq = d_in[2];  const void* bq = d_in[3];
    const void* Wk = d_in[4];  const void* bk = d_in[5];
    const void* Wv = d_in[6];  const void* bv = d_in[7];
    const void* Ws = d_in[8];  const void* bs = d_in[9];
    const void* ln_w = d_in[10];
    const void* ln_b = d_in[11];
    const void* w_lh = d_in[12];
    const void* w_hl = d_in[13];
    const int* ei_high = (const int*)d_in[14];
    const int* ei_low  = (const int*)d_in[15];
    const int* batch   = (const int*)d_in[16];

    // Workspace layout (bytes)
    char* ws = (char*)d_ws;
    const size_t OFF_QKV_LOW  = 0;           // bf16 [N_LOW,384]; l_low overlays later
    const size_t OFF_ACC_LOW  = 201326592;   // f32 [N_LOW,128]
    const size_t OFF_E_LOW    = 335544320;   // f32 [E_LOW,4]
    const size_t OFF_DEN_LOW  = 343932928;   // f32 [N_LOW,4]
    const size_t OFF_QKV_HIGH = 348127232;   // bf16 [N_HIGH,384]; h_high overlays later
    const size_t OFF_ACC_HIGH = 351272960;   // f32 [N_HIGH,128]
    const size_t OFF_E_HIGH   = 353370112;   // f32 [E_HIGH,4]
    const size_t OFF_DEN_HIGH = 354418688;   // f32 [N_HIGH,4]
    const size_t OFF_POOLED   = 354484224;   // f32 [N_HIGH,128]
    const size_t OFF_FLAG     = 356581376;   // int dtype flag
    const size_t WS_NEEDED    = 356581632;
    if (ws_size < WS_NEEDED) return;  // leaves out=0 -> finite err (diagnostic)

    unsigned short* qkv_low  = (unsigned short*)(ws + OFF_QKV_LOW);
    float*          acc_low  = (float*)(ws + OFF_ACC_LOW);
    float*          e_low    = (float*)(ws + OFF_E_LOW);
    float*          den_low  = (float*)(ws + OFF_DEN_LOW);
    unsigned short* qkv_high = (unsigned short*)(ws + OFF_QKV_HIGH);
    float*          acc_high = (float*)(ws + OFF_ACC_HIGH);
    float*          e_high   = (float*)(ws + OFF_E_HIGH);
    float*          den_high = (float*)(ws + OFF_DEN_HIGH);
    float*          pooled   = (float*)(ws + OFF_POOLED);
    int*            dflag    = (int*)(ws + OFF_FLAG);
    unsigned short* l_low  = qkv_low;    // overlay: qkv_low dead after edge_agg
    unsigned short* h_high = qkv_high;   // overlay: qkv_high dead after edge_agg

    hipMemsetAsync(den_low, 0, (size_t)N_LOW * 4 * sizeof(float), stream);
    hipMemsetAsync(den_high, 0, (size_t)N_HIGH * 4 * sizeof(float), stream);

    probe_dtype_kernel<<<1, 256, 0, stream>>>((const unsigned int*)high_emb, dflag);

    gemm_kernel<<<dim3(N_HIGH / 64, 4), 256, 0, stream>>>(
        high_emb, Wq, Wk, Wv, Ws, bq, bk, bv, bs, qkv_high, acc_high, dflag);
    gemm_kernel<<<dim3(N_LOW / 64, 4), 256, 0, stream>>>(
        low_emb, Wq, Wk, Wv, Ws, bq, bk, bv, bs, qkv_low, acc_low, dflag);

    edge_scores_kernel<<<E_HIGH / 4, 256, 0, stream>>>(qkv_high, ei_high, E_HIGH, e_high, den_high);
    edge_scores_kernel<<<E_LOW / 4, 256, 0, stream>>>(qkv_low, ei_low, E_LOW, e_low, den_low);

    edge_agg_kernel<<<E_HIGH / 4, 256, 0, stream>>>(qkv_high, ei_high, E_HIGH, e_high, den_high, acc_high);
    edge_agg_kernel<<<E_LOW / 4, 256, 0, stream>>>(qkv_low, ei_low, E_LOW, e_low, den_low, acc_low);

    ln_relu_kernel<<<N_HIGH / 4, 256, 0, stream>>>(acc_high, ln_w, ln_b, h_high, N_HIGH, dflag);
    ln_relu_kernel<<<N_LOW / 4, 256, 0, stream>>>(acc_low, ln_w, ln_b, l_low, N_LOW, dflag);

    pool_kernel<<<N_HIGH, 128, 0, stream>>>(l_low, batch, pooled);

    high_out_kernel<<<N_HIGH / 4, 256, 0, stream>>>(h_high, pooled, w_lh, d_out, dflag);
    low_out_kernel<<<N_LOW / 4, 256, 0, stream>>>(l_low, h_high, batch, w_hl, d_out, dflag);
}

// Round 4
// 1163.860 us; speedup vs baseline: 1.5574x; 1.5574x over previous
//
#include <hip/hip_runtime.h>
#include <hip/hip_bf16.h>
#include <math.h>

#define N_HIGH 4096
#define N_LOW 262144
#define E_HIGH 65536
#define E_LOW 524288
#define LN_EPS 1e-5f
#define ATT_SCALE 0.17677669529663687f /* 1/sqrt(32) */

typedef short bf16x8 __attribute__((ext_vector_type(8)));
typedef float f32x4 __attribute__((ext_vector_type(4)));

__device__ __forceinline__ float bf2f(unsigned int u) {
    union { unsigned int i; float f; } v; v.i = u << 16; return v.f;
}
__device__ __forceinline__ unsigned short f2bf(float f) {
    union { unsigned int i; float f; } v; v.f = f;
    unsigned int r = (v.i + 0x7fffu + ((v.i >> 16) & 1u)) >> 16;
    return (unsigned short)r;
}
__device__ __forceinline__ float ldf(const void* p, size_t i, int isbf) {
    if (isbf) return bf2f(((const unsigned short*)p)[i]);
    return ((const float*)p)[i];
}
__device__ __forceinline__ float4 load4f(const void* p, size_t i, int isbf) {
    if (isbf) {
        uint2 u = *(const uint2*)((const unsigned short*)p + i);
        float4 r;
        r.x = bf2f(u.x & 0xffffu); r.y = bf2f(u.x >> 16);
        r.z = bf2f(u.y & 0xffffu); r.w = bf2f(u.y >> 16);
        return r;
    }
    return *(const float4*)((const float*)p + i);
}
__device__ __forceinline__ void stf(void* p, size_t i, float v, int isbf) {
    if (isbf) ((unsigned short*)p)[i] = f2bf(v);
    else      ((float*)p)[i] = v;
}

// ---------------------------------------------------------------------------
// Dtype probe (kept from R3 — proven): bits[8:15] of first 256 words.
// ---------------------------------------------------------------------------
__global__ __launch_bounds__(256) void probe_dtype_kernel(
    const unsigned int* __restrict__ x, int* __restrict__ flag)
{
    __shared__ int cnt;
    if (threadIdx.x == 0) cnt = 0;
    __syncthreads();
    unsigned int b = (x[threadIdx.x] >> 8) & 0x7fu;
    if (b >= 60u && b <= 65u) atomicAdd(&cnt, 1);
    __syncthreads();
    if (threadIdx.x == 0) *flag = (cnt >= 128) ? 1 : 0;
}

// ---------------------------------------------------------------------------
// Prep: Wt[g][n][k] = bf16(W_g[k][n]) — one-time transpose+convert so the
// GEMM's B staging is a coalesced row-major copy. grid (4 matrices x 8 slices).
// ---------------------------------------------------------------------------
__global__ __launch_bounds__(256) void prep_wt_kernel(
    const void* __restrict__ Wq, const void* __restrict__ Wk,
    const void* __restrict__ Wv, const void* __restrict__ Ws,
    unsigned short* __restrict__ Wt, const int* __restrict__ dflag)
{
    const int isbf = *dflag;
    const int g = blockIdx.x >> 3;
    const int slice = blockIdx.x & 7;          // 16 k-rows per slice
    const void* W = (g == 0) ? Wq : (g == 1) ? Wk : (g == 2) ? Wv : Ws;
    #pragma unroll
    for (int i = 0; i < 8; ++i) {
        int linear = i * 256 + threadIdx.x;    // 0..2047
        int k = slice * 16 + (linear >> 7);    // 0..127
        int n = linear & 127;
        float v = ldf(W, (size_t)k * 128 + n, isbf);
        Wt[((size_t)g * 128 + n) * 128 + k] = f2bf(v);
    }
}

// ---------------------------------------------------------------------------
// MFMA projection GEMM. Tile 64(M) x 128(N), K=128 one-shot, c-loop over the
// four weight matrices. 4 waves: wm=(w&1)*32, wn=(w>>1)*64; each wave 32x64
// via 2x4 tiles of 16x16x32. LDS: As 64x136 + Bs 128x136 = 52 KB (pad +8
// ushorts keeps b128 16B-aligned and bank spread).
// q,k,v -> bf16 qkv[M,384]; skip -> fp32 accv[M,128].
// ---------------------------------------------------------------------------
__global__ __launch_bounds__(256) void gemm_mfma_kernel(
    const void* __restrict__ x, const unsigned short* __restrict__ Wt,
    const void* __restrict__ bq, const void* __restrict__ bk,
    const void* __restrict__ bv, const void* __restrict__ bs,
    unsigned short* __restrict__ qkv, float* __restrict__ accv,
    const int* __restrict__ dflag)
{
    __shared__ unsigned short As[64 * 136];
    __shared__ unsigned short Bs[128 * 136];
    const int isbf = *dflag;
    const int tid = threadIdx.x;
    const int m0 = blockIdx.x * 64;

    // Stage A (64x128), fp32->bf16
    #pragma unroll
    for (int i = 0; i < 8; ++i) {
        int linear = i * 256 + tid;            // 0..2047
        int row = linear >> 5;                 // 0..63
        int c4 = (linear & 31) << 2;           // 0..124
        float4 v = load4f(x, (size_t)(m0 + row) * 128 + c4, isbf);
        ushort4 s;
        s.x = f2bf(v.x); s.y = f2bf(v.y); s.z = f2bf(v.z); s.w = f2bf(v.w);
        *(ushort4*)&As[row * 136 + c4] = s;
    }

    const void* blist[4] = { bq, bk, bv, bs };

    const int lane = tid & 63;
    const int w = tid >> 6;
    const int wm = (w & 1) * 32;
    const int wn = (w >> 1) * 64;
    const int lr = lane & 15;
    const int lk = (lane >> 4) * 8;
    const int rbase = (lane >> 4) * 4;

    for (int c = 0; c < 4; ++c) {
        __syncthreads();  // protect Bs reuse (and As visibility on c=0)
        // Stage B from Wt: row-major copy, 16B vector ops
        #pragma unroll
        for (int i = 0; i < 8; ++i) {
            int linear = i * 256 + tid;        // 0..2047
            int n = linear >> 4;               // 0..127
            int c8 = (linear & 15) << 3;       // 0..120
            uint4 v = *(const uint4*)&Wt[((size_t)c * 128 + n) * 128 + c8];
            *(uint4*)&Bs[n * 136 + c8] = v;
        }
        __syncthreads();

        f32x4 acc[2][4];
        #pragma unroll
        for (int a = 0; a < 2; ++a)
            #pragma unroll
            for (int b = 0; b < 4; ++b) acc[a][b] = (f32x4){0.f, 0.f, 0.f, 0.f};

        #pragma unroll
        for (int kk = 0; kk < 4; ++kk) {
            int k0 = kk * 32 + lk;
            bf16x8 af[2], bfv[4];
            #pragma unroll
            for (int im = 0; im < 2; ++im)
                af[im] = *(const bf16x8*)&As[(wm + im * 16 + lr) * 136 + k0];
            #pragma unroll
            for (int in = 0; in < 4; ++in)
                bfv[in] = *(const bf16x8*)&Bs[(wn + in * 16 + lr) * 136 + k0];
            #pragma unroll
            for (int im = 0; im < 2; ++im)
                #pragma unroll
                for (int in = 0; in < 4; ++in)
                    acc[im][in] = __builtin_amdgcn_mfma_f32_16x16x32_bf16(
                        af[im], bfv[in], acc[im][in], 0, 0, 0);
        }

        float bias[4];
        #pragma unroll
        for (int in = 0; in < 4; ++in) bias[in] = ldf(blist[c], wn + in * 16 + lr, isbf);

        #pragma unroll
        for (int im = 0; im < 2; ++im) {
            #pragma unroll
            for (int r = 0; r < 4; ++r) {
                int m = wm + im * 16 + rbase + r;
                size_t row = (size_t)(m0 + m);
                #pragma unroll
                for (int in = 0; in < 4; ++in) {
                    int n = wn + in * 16 + lr;
                    float val = acc[im][in][r] + bias[in];
                    if (c < 3) qkv[row * 384 + c * 128 + n] = f2bf(val);
                    else       accv[row * 128 + n] = val;
                }
            }
        }
    }
}

// ---------------------------------------------------------------------------
// Edge pass B: per-head scores -> e = exp(score*scale); denom += e
// ---------------------------------------------------------------------------
__global__ __launch_bounds__(256) void edge_scores_kernel(
    const unsigned short* __restrict__ qkv, const int* __restrict__ ei, int E,
    float* __restrict__ ebuf, float* __restrict__ denom)
{
    int lane = threadIdx.x & 63;
    int e = blockIdx.x * 4 + (threadIdx.x >> 6);
    if (e >= E) return;
    int src = ei[e];
    int dst = ei[E + e];
    const unsigned short* qp = qkv + (long)dst * 384;
    const unsigned short* kp = qkv + (long)src * 384 + 128;
    ushort2 qa = *(const ushort2*)(qp + 2 * lane);
    ushort2 kb = *(const ushort2*)(kp + 2 * lane);
    float partial = bf2f(qa.x) * bf2f(kb.x) + bf2f(qa.y) * bf2f(kb.y);
    #pragma unroll
    for (int m = 1; m < 16; m <<= 1) partial += __shfl_xor(partial, m, 64);
    if ((lane & 15) == 0) {
        int h = lane >> 4;
        float z = partial * ATT_SCALE;
        z = fminf(fmaxf(z, -60.f), 60.f);
        float ev = __expf(z);
        ebuf[(long)e * 4 + h] = ev;
        unsafeAtomicAdd(&denom[(long)dst * 4 + h], ev);
    }
}

// ---------------------------------------------------------------------------
// Edge pass C: acc[dst] += (e/denom[dst]) * v[src]
// ---------------------------------------------------------------------------
__global__ __launch_bounds__(256) void edge_agg_kernel(
    const unsigned short* __restrict__ qkv, const int* __restrict__ ei, int E,
    const float* __restrict__ ebuf, const float* __restrict__ denom,
    float* __restrict__ acc)
{
    int lane = threadIdx.x & 63;
    int e = blockIdx.x * 4 + (threadIdx.x >> 6);
    if (e >= E) return;
    int src = ei[e];
    int dst = ei[E + e];
    int h = lane >> 4;
    float d = fmaxf(denom[(long)dst * 4 + h], 1e-30f);
    float alpha = ebuf[(long)e * 4 + h] / d;
    ushort2 vv = *(const ushort2*)(qkv + (long)src * 384 + 256 + 2 * lane);
    float* ap = acc + (long)dst * 128 + 2 * lane;
    unsafeAtomicAdd(ap, alpha * bf2f(vv.x));
    unsafeAtomicAdd(ap + 1, alpha * bf2f(vv.y));
}

// ---------------------------------------------------------------------------
// LayerNorm + ReLU -> bf16 internal; one wave per node
// ---------------------------------------------------------------------------
__global__ __launch_bounds__(256) void ln_relu_kernel(
    const float* __restrict__ acc, const void* __restrict__ lnw,
    const void* __restrict__ lnb, unsigned short* __restrict__ out, int N,
    const int* __restrict__ dflag)
{
    const int isbf = *dflag;
    int lane = threadIdx.x & 63;
    int n = blockIdx.x * 4 + (threadIdx.x >> 6);
    if (n >= N) return;
    float2 v = *(const float2*)(acc + (long)n * 128 + 2 * lane);
    float s = v.x + v.y;
    float q = v.x * v.x + v.y * v.y;
    #pragma unroll
    for (int m = 1; m < 64; m <<= 1) { s += __shfl_xor(s, m, 64); q += __shfl_xor(q, m, 64); }
    float mean = s * (1.f / 128.f);
    float var = fmaxf(q * (1.f / 128.f) - mean * mean, 0.f);
    float rs = rsqrtf(var + LN_EPS);
    float w0 = ldf(lnw, 2 * lane, isbf), w1 = ldf(lnw, 2 * lane + 1, isbf);
    float b0 = ldf(lnb, 2 * lane, isbf), b1 = ldf(lnb, 2 * lane + 1, isbf);
    float y0 = fmaxf((v.x - mean) * rs * w0 + b0, 0.f);
    float y1 = fmaxf((v.y - mean) * rs * w1 + b1, 0.f);
    unsigned short* o = out + (long)n * 128 + 2 * lane;
    o[0] = f2bf(y0);
    o[1] = f2bf(y1);
}

// ---------------------------------------------------------------------------
// global_mean_pool over sorted batch; one block (128 thr) per high node
// ---------------------------------------------------------------------------
__global__ __launch_bounds__(128) void pool_kernel(
    const unsigned short* __restrict__ l, const int* __restrict__ batch,
    float* __restrict__ pooled)
{
    __shared__ int se[2];
    int g = blockIdx.x;
    if (threadIdx.x == 0) {
        int lo = 0, hi = N_LOW;
        while (lo < hi) { int mid = (lo + hi) >> 1; if (batch[mid] < g) lo = mid + 1; else hi = mid; }
        se[0] = lo;
        hi = N_LOW;
        while (lo < hi) { int mid = (lo + hi) >> 1; if (batch[mid] < g + 1) lo = mid + 1; else hi = mid; }
        se[1] = lo;
    }
    __syncthreads();
    int start = se[0], end = se[1];
    int d = threadIdx.x;
    float ssum = 0.f;
    for (int r = start; r < end; ++r) ssum += bf2f(l[(long)r * 128 + d]);
    int cnt = end - start;
    pooled[(long)g * 128 + d] = ssum / (float)(cnt > 0 ? cnt : 1);
}

// ---------------------------------------------------------------------------
// high_out = sim*h + (1-sim)*pooled, sim = sigmoid([h,pooled]@w_lh)
// ---------------------------------------------------------------------------
__global__ __launch_bounds__(256) void high_out_kernel(
    const unsigned short* __restrict__ h, const float* __restrict__ pooled,
    const void* __restrict__ wlh, void* __restrict__ out,
    const int* __restrict__ dflag)
{
    const int isbf = *dflag;
    int lane = threadIdx.x & 63;
    int n = blockIdx.x * 4 + (threadIdx.x >> 6);
    if (n >= N_HIGH) return;
    float h0 = bf2f(h[(long)n * 128 + 2 * lane]);
    float h1 = bf2f(h[(long)n * 128 + 2 * lane + 1]);
    float2 pv = *(const float2*)(pooled + (long)n * 128 + 2 * lane);
    float s = h0 * ldf(wlh, 2 * lane, isbf) + h1 * ldf(wlh, 2 * lane + 1, isbf)
            + pv.x * ldf(wlh, 128 + 2 * lane, isbf) + pv.y * ldf(wlh, 128 + 2 * lane + 1, isbf);
    #pragma unroll
    for (int m = 1; m < 64; m <<= 1) s += __shfl_xor(s, m, 64);
    float sim = 1.f / (1.f + __expf(-s));
    stf(out, (size_t)n * 128 + 2 * lane,     sim * h0 + (1.f - sim) * pv.x, isbf);
    stf(out, (size_t)n * 128 + 2 * lane + 1, sim * h1 + (1.f - sim) * pv.y, isbf);
}

// ---------------------------------------------------------------------------
// low_out = a*l + (1-a)*h[batch], a = sigmoid([hb,l]@w_hl)
// ---------------------------------------------------------------------------
__global__ __launch_bounds__(256) void low_out_kernel(
    const unsigned short* __restrict__ l, const unsigned short* __restrict__ h,
    const int* __restrict__ batch, const void* __restrict__ whl,
    void* __restrict__ out, const int* __restrict__ dflag)
{
    const int isbf = *dflag;
    int lane = threadIdx.x & 63;
    int n = blockIdx.x * 4 + (threadIdx.x >> 6);
    if (n >= N_LOW) return;
    int g = batch[n];
    float l0 = bf2f(l[(long)n * 128 + 2 * lane]);
    float l1 = bf2f(l[(long)n * 128 + 2 * lane + 1]);
    float h0 = bf2f(h[(long)g * 128 + 2 * lane]);
    float h1 = bf2f(h[(long)g * 128 + 2 * lane + 1]);
    float s = h0 * ldf(whl, 2 * lane, isbf) + h1 * ldf(whl, 2 * lane + 1, isbf)
            + l0 * ldf(whl, 128 + 2 * lane, isbf) + l1 * ldf(whl, 128 + 2 * lane + 1, isbf);
    #pragma unroll
    for (int m = 1; m < 64; m <<= 1) s += __shfl_xor(s, m, 64);
    float a = 1.f / (1.f + __expf(-s));
    size_t base = (size_t)N_HIGH * 128 + (size_t)n * 128 + 2 * lane;
    stf(out, base,     a * l0 + (1.f - a) * h0, isbf);
    stf(out, base + 1, a * l1 + (1.f - a) * h1, isbf);
}

// ---------------------------------------------------------------------------
extern "C" void kernel_launch(void* const* d_in, const int* in_sizes, int n_in,
                              void* d_out, int out_size, void* d_ws, size_t ws_size,
                              hipStream_t stream)
{
    const void* high_emb = d_in[0];
    const void* low_emb  = d_in[1];
    const void* Wq = d_in[2];  const void* bq = d_in[3];
    const void* Wk = d_in[4];  const void* bk = d_in[5];
    const void* Wv = d_in[6];  const void* bv = d_in[7];
    const void* Ws = d_in[8];  const void* bs = d_in[9];
    const void* ln_w = d_in[10];
    const void* ln_b = d_in[11];
    const void* w_lh = d_in[12];
    const void* w_hl = d_in[13];
    const int* ei_high = (const int*)d_in[14];
    const int* ei_low  = (const int*)d_in[15];
    const int* batch   = (const int*)d_in[16];

    // Workspace layout (bytes) — unchanged from the proven R3 layout.
    char* ws = (char*)d_ws;
    const size_t OFF_QKV_LOW  = 0;           // bf16 [N_LOW,384]; l_low overlays later
    const size_t OFF_ACC_LOW  = 201326592;   // f32 [N_LOW,128]
    const size_t OFF_E_LOW    = 335544320;   // f32 [E_LOW,4]; Wt (256KB bf16) overlays BEFORE edge_scores
    const size_t OFF_DEN_LOW  = 343932928;   // f32 [N_LOW,4]
    const size_t OFF_QKV_HIGH = 348127232;   // bf16 [N_HIGH,384]; h_high overlays later
    const size_t OFF_ACC_HIGH = 351272960;   // f32 [N_HIGH,128]
    const size_t OFF_E_HIGH   = 353370112;   // f32 [E_HIGH,4]
    const size_t OFF_DEN_HIGH = 354418688;   // f32 [N_HIGH,4]
    const size_t OFF_POOLED   = 354484224;   // f32 [N_HIGH,128]
    const size_t OFF_FLAG     = 356581376;   // int dtype flag
    const size_t WS_NEEDED    = 356581632;
    if (ws_size < WS_NEEDED) return;

    unsigned short* qkv_low  = (unsigned short*)(ws + OFF_QKV_LOW);
    float*          acc_low  = (float*)(ws + OFF_ACC_LOW);
    float*          e_low    = (float*)(ws + OFF_E_LOW);
    float*          den_low  = (float*)(ws + OFF_DEN_LOW);
    unsigned short* qkv_high = (unsigned short*)(ws + OFF_QKV_HIGH);
    float*          acc_high = (float*)(ws + OFF_ACC_HIGH);
    float*          e_high   = (float*)(ws + OFF_E_HIGH);
    float*          den_high = (float*)(ws + OFF_DEN_HIGH);
    float*          pooled   = (float*)(ws + OFF_POOLED);
    int*            dflag    = (int*)(ws + OFF_FLAG);
    unsigned short* Wt       = (unsigned short*)(ws + OFF_E_LOW);  // dead before e_low written
    unsigned short* l_low  = qkv_low;    // overlay: qkv_low dead after edge_agg
    unsigned short* h_high = qkv_high;   // overlay: qkv_high dead after edge_agg

    hipMemsetAsync(den_low, 0, (size_t)N_LOW * 4 * sizeof(float), stream);
    hipMemsetAsync(den_high, 0, (size_t)N_HIGH * 4 * sizeof(float), stream);

    probe_dtype_kernel<<<1, 256, 0, stream>>>((const unsigned int*)high_emb, dflag);

    prep_wt_kernel<<<32, 256, 0, stream>>>(Wq, Wk, Wv, Ws, Wt, dflag);

    gemm_mfma_kernel<<<N_HIGH / 64, 256, 0, stream>>>(
        high_emb, Wt, bq, bk, bv, bs, qkv_high, acc_high, dflag);
    gemm_mfma_kernel<<<N_LOW / 64, 256, 0, stream>>>(
        low_emb, Wt, bq, bk, bv, bs, qkv_low, acc_low, dflag);

    edge_scores_kernel<<<E_HIGH / 4, 256, 0, stream>>>(qkv_high, ei_high, E_HIGH, e_high, den_high);
    edge_scores_kernel<<<E_LOW / 4, 256, 0, stream>>>(qkv_low, ei_low, E_LOW, e_low, den_low);

    edge_agg_kernel<<<E_HIGH / 4, 256, 0, stream>>>(qkv_high, ei_high, E_HIGH, e_high, den_high, acc_high);
    edge_agg_kernel<<<E_LOW / 4, 256, 0, stream>>>(qkv_low, ei_low, E_LOW, e_low, den_low, acc_low);

    ln_relu_kernel<<<N_HIGH / 4, 256, 0, stream>>>(acc_high, ln_w, ln_b, h_high, N_HIGH, dflag);
    ln_relu_kernel<<<N_LOW / 4, 256, 0, stream>>>(acc_low, ln_w, ln_b, l_low, N_LOW, dflag);

    pool_kernel<<<N_HIGH, 128, 0, stream>>>(l_low, batch, pooled);

    high_out_kernel<<<N_HIGH / 4, 256, 0, stream>>>(h_high, pooled, w_lh, d_out, dflag);
    low_out_kernel<<<N_LOW / 4, 256, 0, stream>>>(l_low, h_high, batch, w_hl, d_out, dflag);
}